// Round 12
// baseline (655.707 us; speedup 1.0000x reference)
//
#include <hip/hip_runtime.h>

#define N_NODES 50000
#define N_EDGES 800000
#define IN_DIM  64
#define EDGE_DIM 16
#define HID     128
#define NLAYERS 3
#define NGRAPH  128
#define EPS     1e-5f

#define BSHIFT  7
#define NB      391        // ceil(50000/128)
#define BCAP    4064       // bucket capacity (mean 2048, sd ~45)

typedef __attribute__((ext_vector_type(8))) short bf8_t;
typedef __attribute__((ext_vector_type(4))) short bf4_t;
typedef __attribute__((ext_vector_type(4))) float f32x4;

__device__ __forceinline__ unsigned short f2bf(float x) {
    unsigned u = __float_as_uint(x);
    unsigned r = u + 0x7fffu + ((u >> 16) & 1u);   // round-to-nearest-even
    return (unsigned short)(r >> 16);
}
__device__ __forceinline__ float bf2f(unsigned short v) {
    return __uint_as_float(((unsigned)v) << 16);
}

// ==================== init (+ per-graph counts in block 0) ====================
__global__ void k_init(int* __restrict__ bcnt_pad, float* __restrict__ pool,
                       float* __restrict__ gsum, float* __restrict__ gsq,
                       const int* __restrict__ batch, float* __restrict__ cnt) {
    int i = blockIdx.x * blockDim.x + threadIdx.x;
    if (i < NB * 16) bcnt_pad[i] = 0;
    if (i < NGRAPH * HID) pool[i] = 0.0f;
    if (i < NLAYERS * NGRAPH * HID) { gsum[i] = 0.0f; gsq[i] = 0.0f; }
    if (blockIdx.x == 0 && threadIdx.x < NGRAPH) {
        int g = threadIdx.x;
        int lo = 0, hi = N_NODES;
        while (lo < hi) { int mid = (lo + hi) >> 1; if (batch[mid] < g) lo = mid + 1; else hi = mid; }
        int a = lo;
        lo = 0; hi = N_NODES;
        while (lo < hi) { int mid = (lo + hi) >> 1; if (batch[mid] < g + 1) lo = mid + 1; else hi = mid; }
        cnt[g] = (float)(lo - a);
    }
}

// ==================== all weight conversions in one kernel ====================
// [0,98304): nn wt ; [98304,147456): encoder ; [147456,159744): edge wte
__global__ void k_wall(const float* __restrict__ nw1, const float* __restrict__ nw2,
                       const float* __restrict__ lw1, const float* __restrict__ pw1,
                       const float* __restrict__ lw2, const float* __restrict__ pw2,
                       const float* __restrict__ ew, const float* __restrict__ eb,
                       unsigned short* __restrict__ wt,
                       unsigned short* __restrict__ we,
                       unsigned short* __restrict__ wte) {
    int idx = blockIdx.x * 256 + threadIdx.x;
    if (idx < 98304) {
        int k = idx & 127;
        int n = (idx >> 7) & 127;
        int which = (idx >> 14) & 1;
        int l = idx >> 15;
        const float* w = (which == 0 ? nw1 : nw2) + l * HID * HID;
        wt[idx] = f2bf(w[k * HID + n]);
    } else if (idx < 147456) {
        int r0 = idx - 98304;
        float v;
        if (r0 < 8192)       { int n = r0 >> 6, k = r0 & 63;            v = lw1[k * HID + n]; }
        else if (r0 < 16384) { int r = r0 - 8192;  int n = r >> 6, k = r & 63;  v = pw1[k * HID + n]; }
        else if (r0 < 32768) { int r = r0 - 16384; int n = r >> 7, k = r & 127; v = lw2[k * HID + n]; }
        else                 { int r = r0 - 32768; int n = r >> 7, k = r & 127; v = pw2[k * HID + n]; }
        we[r0] = f2bf(v);
    } else if (idx < 159744) {
        int r0 = idx - 147456;
        int j = r0 & 7;
        int lane = (r0 >> 3) & 63;
        int t = (r0 >> 9) & 7;
        int l = r0 >> 12;
        int k = (lane >> 4) * 8 + j;
        int feat = t * 16 + (lane & 15);
        float v = 0.0f;
        if (k < EDGE_DIM)       v = ew[l * EDGE_DIM * HID + k * HID + feat];
        else if (k == EDGE_DIM) v = eb[l * HID + feat];
        wte[r0] = f2bf(v);
    }
}

// ==================== bucket scatter: edge -> bucket (dst>>7), packed {src, dl<<20|eid} ====================
__global__ void k_bfill(const int* __restrict__ srcs, const int* __restrict__ dsts,
                        int* __restrict__ bcnt_pad, int2* __restrict__ bkt) {
    int e = blockIdx.x * blockDim.x + threadIdx.x;
    if (e < N_EDGES) {
        int d = dsts[e];
        int b = d >> BSHIFT;
        int pos = atomicAdd(&bcnt_pad[b * 16], 1);
        if (pos < BCAP)
            bkt[(size_t)b * BCAP + pos] = make_int2(srcs[e], ((d & 127) << 20) | e);
    }
}

// ==================== scan bucket counts -> boff ====================
__global__ __launch_bounds__(512) void k_bscan(const int* __restrict__ bcnt_pad,
                                               int* __restrict__ boff) {
    __shared__ int s[512];
    int t = threadIdx.x;
    int v = (t < NB) ? bcnt_pad[t * 16] : 0;
    s[t] = v; __syncthreads();
    for (int off = 1; off < 512; off <<= 1) {
        int x = (t >= off) ? s[t - off] : 0;
        __syncthreads();
        s[t] += x;
        __syncthreads();
    }
    if (t < NB) boff[t] = s[t] - v;
    if (t == NB - 1) boff[NB] = s[t];
}

// ==================== per-bucket CSR build + fused edge-attr reorder ====================
// local hist+scan -> row bounds; scatter writes csr_src + bf16 cea directly.
__global__ __launch_bounds__(256) void k_bcsr(const int* __restrict__ bcnt_pad,
                                              const int* __restrict__ boff,
                                              const int2* __restrict__ bkt,
                                              const float* __restrict__ ea,
                                              int* __restrict__ row_start,
                                              int* __restrict__ row_end,
                                              int* __restrict__ csr_src,
                                              unsigned short* __restrict__ cea) {
    __shared__ int lcnt[128];
    __shared__ int lsc[128];
    __shared__ int lfill[128];
    int b = blockIdx.x, t = threadIdx.x;
    int base = boff[b];
    int ecnt = bcnt_pad[b * 16]; if (ecnt > BCAP) ecnt = BCAP;
    if (t < 128) lcnt[t] = 0;
    __syncthreads();
    for (int i = t; i < ecnt; i += 256) {
        int2 en = bkt[(size_t)b * BCAP + i];
        atomicAdd(&lcnt[(en.y >> 20) & 127], 1);
    }
    __syncthreads();
    if (t < 128) lsc[t] = lcnt[t];
    __syncthreads();
    for (int off = 1; off < 128; off <<= 1) {
        int x = (t < 128 && t >= off) ? lsc[t - off] : 0;
        __syncthreads();
        if (t < 128) lsc[t] += x;
        __syncthreads();
    }
    if (t < 128) {
        int excl = lsc[t] - lcnt[t];
        lfill[t] = excl;
        int node = (b << BSHIFT) + t;
        if (node < N_NODES) {
            row_start[node] = base + excl;
            row_end[node]   = base + excl + lcnt[t];
        }
    }
    __syncthreads();
    for (int i = t; i < ecnt; i += 256) {
        int2 en = bkt[(size_t)b * BCAP + i];
        int q = atomicAdd(&lfill[(en.y >> 20) & 127], 1);
        int p = base + q;
        csr_src[p] = en.x;
        int eid = en.y & 0xFFFFF;
        const float* s = ea + (size_t)eid * EDGE_DIM;
        float4 a0 = *(const float4*)(s);
        float4 a1 = *(const float4*)(s + 4);
        float4 a2 = *(const float4*)(s + 8);
        float4 a3 = *(const float4*)(s + 12);
        bf8_t v0, v1;
        v0[0] = (short)f2bf(a0.x); v0[1] = (short)f2bf(a0.y);
        v0[2] = (short)f2bf(a0.z); v0[3] = (short)f2bf(a0.w);
        v0[4] = (short)f2bf(a1.x); v0[5] = (short)f2bf(a1.y);
        v0[6] = (short)f2bf(a1.z); v0[7] = (short)f2bf(a1.w);
        v1[0] = (short)f2bf(a2.x); v1[1] = (short)f2bf(a2.y);
        v1[2] = (short)f2bf(a2.z); v1[3] = (short)f2bf(a2.w);
        v1[4] = (short)f2bf(a3.x); v1[5] = (short)f2bf(a3.y);
        v1[6] = (short)f2bf(a3.z); v1[7] = (short)f2bf(a3.w);
        *(bf8_t*)(cea + (size_t)p * EDGE_DIM) = v0;
        *(bf8_t*)(cea + (size_t)p * EDGE_DIM + 8) = v1;
    }
}

// ==================== encoder v2: role-split waves (lig XOR prot per wave) ====================
#define HS 136   // LDS row stride in shorts
__global__ __launch_bounds__(256, 8) void k_encoder_mfma(
    const float* __restrict__ x,
    const unsigned short* __restrict__ we,
    const float* __restrict__ lb1, const float* __restrict__ lb2,
    const float* __restrict__ pb1, const float* __restrict__ pb2,
    unsigned short* __restrict__ Hbp) {
    __shared__ short h1s[4][16 * HS];
    int w = threadIdx.x >> 6, lane = threadIdx.x & 63;
    int m = lane & 15, quad = lane >> 4;
    int tile = w >> 1, role = w & 1;
    int nb = blockIdx.x * 32 + tile * 16;
    short* hl = h1s[w];
    int nclamp = nb + m; if (nclamp >= N_NODES) nclamp = N_NODES - 1;
    const float* xp = x + (size_t)nclamp * IN_DIM;
    const float* b1 = role ? pb1 : lb1;
    const float* b2 = role ? pb2 : lb2;
    const unsigned short* w1 = we + role * 8192;
    const unsigned short* w2 = we + 16384 + role * 16384;

    f32x4 a1[8];
    #pragma unroll
    for (int t = 0; t < 8; ++t) {
        float bv = b1[t * 16 + m];
        a1[t] = (f32x4){bv, bv, bv, bv};
    }
    #pragma unroll
    for (int s_ = 0; s_ < 2; ++s_) {
        int k0 = s_ * 32 + quad * 8;
        float4 a0 = *(const float4*)(xp + k0);
        float4 a1v = *(const float4*)(xp + k0 + 4);
        bf8_t af;
        af[0] = (short)f2bf(a0.x); af[1] = (short)f2bf(a0.y);
        af[2] = (short)f2bf(a0.z); af[3] = (short)f2bf(a0.w);
        af[4] = (short)f2bf(a1v.x); af[5] = (short)f2bf(a1v.y);
        af[6] = (short)f2bf(a1v.z); af[7] = (short)f2bf(a1v.w);
        #pragma unroll
        for (int t = 0; t < 8; ++t) {
            bf8_t bw = *(const bf8_t*)(w1 + (t * 16 + m) * 64 + k0);
            a1[t] = __builtin_amdgcn_mfma_f32_16x16x32_bf16(af, bw, a1[t], 0, 0, 0);
        }
    }
    #pragma unroll
    for (int t = 0; t < 8; ++t)
        #pragma unroll
        for (int r = 0; r < 4; ++r)
            hl[(quad * 4 + r) * HS + t * 16 + m] = (short)f2bf(fmaxf(a1[t][r], 0.0f));
    __syncthreads();
    f32x4 a2[8];
    #pragma unroll
    for (int t = 0; t < 8; ++t) {
        float bv = b2[t * 16 + m];
        a2[t] = (f32x4){bv, bv, bv, bv};
    }
    #pragma unroll
    for (int s_ = 0; s_ < 4; ++s_) {
        int k0 = s_ * 32 + quad * 8;
        bf8_t af = *(const bf8_t*)(hl + m * HS + k0);
        #pragma unroll
        for (int t = 0; t < 8; ++t) {
            bf8_t bw = *(const bf8_t*)(w2 + (t * 16 + m) * 128 + k0);
            a2[t] = __builtin_amdgcn_mfma_f32_16x16x32_bf16(af, bw, a2[t], 0, 0, 0);
        }
    }
    #pragma unroll
    for (int r = 0; r < 4; ++r) {
        int node = nb + quad * 4 + r;
        if (node < N_NODES) {
            bool prot = x[(size_t)node * IN_DIM + (IN_DIM - 1)] > 0.5f;
            if (prot == (role == 1)) {
                bf8_t o;
                #pragma unroll
                for (int t = 0; t < 8; ++t)
                    o[t] = (short)f2bf(fmaxf(a2[t][r], 0.0f));
                *(bf8_t*)(Hbp + (size_t)node * HID + m * 8) = o;
            }
        }
    }
}

// ==================== edge gather v9 (proven 57us / 131MB floor) ====================
// Each 64-lane wave handles ONE node and HALF (64) of the output features.
// eb folded into wte k==16 row via af[0]=1.0 at quad==2.
__global__ __launch_bounds__(256, 8) void k_gather(
    const int* __restrict__ csr_src, const unsigned short* __restrict__ cea,
    const int* __restrict__ row_start, const int* __restrict__ row_end,
    const unsigned short* __restrict__ wte,
    const unsigned short* __restrict__ Hbp, unsigned short* __restrict__ Abp) {
    int w = threadIdx.x >> 6, lane = threadIdx.x & 63;
    int m = lane & 15, quad = lane >> 4;
    int n = blockIdx.x * 2 + (w >> 1);
    int half = w & 1;

    bf8_t bw[4];
    #pragma unroll
    for (int t = 0; t < 4; ++t)
        bw[t] = *(const bf8_t*)(wte + ((size_t)(half * 4 + t) * 64 + lane) * 8);

    float acc[4];
    #pragma unroll
    for (int t = 0; t < 4; ++t) acc[t] = 0.0f;

    int p  = __builtin_amdgcn_readfirstlane(row_start[n]);
    int pe = __builtin_amdgcn_readfirstlane(row_end[n]);

    const f32x4 zc = (f32x4){0.0f, 0.0f, 0.0f, 0.0f};

    for (; p + 16 <= pe; p += 16) {
        bf8_t af = (bf8_t){0, 0, 0, 0, 0, 0, 0, 0};
        if (quad < 2)
            af = *(const bf8_t*)(cea + (size_t)(p + m) * EDGE_DIM + quad * 8);
        else if (quad == 2)
            af[0] = (short)0x3F80;   // 1.0 bf16 -> multiplies eb row (k==16)
        int sr[4];
        #pragma unroll
        for (int r = 0; r < 4; ++r) sr[r] = csr_src[p + quad * 4 + r];
        bf4_t hrow[4];
        #pragma unroll
        for (int r = 0; r < 4; ++r)
            hrow[r] = *(const bf4_t*)(Hbp + (size_t)sr[r] * HID + m * 8 + half * 4);
        f32x4 d[4];
        #pragma unroll
        for (int t = 0; t < 4; ++t)
            d[t] = __builtin_amdgcn_mfma_f32_16x16x32_bf16(af, bw[t], zc, 0, 0, 0);
        #pragma unroll
        for (int t = 0; t < 4; ++t)
            #pragma unroll
            for (int r = 0; r < 4; ++r)
                acc[t] += fmaxf(bf2f((unsigned short)hrow[r][t]) + d[t][r], 0.0f);
    }
    int rem = pe - p;
    if (rem > 0) {
        bf8_t af = (bf8_t){0, 0, 0, 0, 0, 0, 0, 0};
        if (quad < 2 && m < rem)
            af = *(const bf8_t*)(cea + (size_t)(p + m) * EDGE_DIM + quad * 8);
        else if (quad == 2)
            af[0] = (short)0x3F80;
        int sr[4];
        #pragma unroll
        for (int r = 0; r < 4; ++r) {
            int idx = p + quad * 4 + r; if (idx >= pe) idx = pe - 1;
            sr[r] = csr_src[idx];
        }
        bf4_t hrow[4];
        #pragma unroll
        for (int r = 0; r < 4; ++r)
            hrow[r] = *(const bf4_t*)(Hbp + (size_t)sr[r] * HID + m * 8 + half * 4);
        f32x4 d[4];
        #pragma unroll
        for (int t = 0; t < 4; ++t)
            d[t] = __builtin_amdgcn_mfma_f32_16x16x32_bf16(af, bw[t], zc, 0, 0, 0);
        #pragma unroll
        for (int t = 0; t < 4; ++t)
            #pragma unroll
            for (int r = 0; r < 4; ++r)
                if (quad * 4 + r < rem)
                    acc[t] += fmaxf(bf2f((unsigned short)hrow[r][t]) + d[t][r], 0.0f);
    }
    #pragma unroll
    for (int t = 0; t < 4; ++t) {
        acc[t] += __shfl_xor(acc[t], 16);
        acc[t] += __shfl_xor(acc[t], 32);
    }
    // lane (quad,m) writes feature (half*4+quad)*16 + m ; add self term from Hbp
    float asel = (quad == 0) ? acc[0] : (quad == 1) ? acc[1] : (quad == 2) ? acc[2] : acc[3];
    float self_ = bf2f(Hbp[(size_t)n * HID + m * 8 + half * 4 + quad]);
    Abp[(size_t)n * HID + (half * 4 + quad) * 16 + m] = f2bf(asel + self_);
}

// ==================== node MLP v2: feature-split wave pairs (A bf16 in, H bf16 out) ====================
// Wave pair (tile, role): role computes output features role*64..role*64+63 of BOTH
// layers for the pair's 16 nodes. Layer-1 halves meet in the shared LDS h1 tile.
#define MLP_NODES_PER_BLOCK 32
__global__ __launch_bounds__(256, 6) void k_mlp_mfma(
    const unsigned short* __restrict__ Abp, const int* __restrict__ batch,
    const unsigned short* __restrict__ wt1, const unsigned short* __restrict__ wt2,
    const float* __restrict__ b1, const float* __restrict__ b2,
    unsigned short* __restrict__ Hb, float* __restrict__ gsum, float* __restrict__ gsq) {
    __shared__ short h1s[2][16 * HS];
    int w = threadIdx.x >> 6;
    int lane = threadIdx.x & 63;
    int m = lane & 15;
    int quad = lane >> 4;
    int tile = w >> 1, role = w & 1;
    int nb = blockIdx.x * MLP_NODES_PER_BLOCK + tile * 16;
    short* hw = h1s[tile];
    int fbase = role * 64;

    int nclamp = nb + m; if (nclamp >= N_NODES) nclamp = N_NODES - 1;
    const unsigned short* Ap = Abp + (size_t)nclamp * HID;
    f32x4 acc1[4];
    #pragma unroll
    for (int t = 0; t < 4; ++t) {
        float bv = b1[fbase + t * 16 + m];
        acc1[t] = (f32x4){bv, bv, bv, bv};
    }
    #pragma unroll
    for (int s_ = 0; s_ < 4; ++s_) {
        int k0 = s_ * 32 + quad * 8;
        bf8_t af = *(const bf8_t*)(Ap + k0);
        #pragma unroll
        for (int t = 0; t < 4; ++t) {
            bf8_t bf = *(const bf8_t*)(wt1 + (size_t)(fbase + t * 16 + m) * HID + k0);
            acc1[t] = __builtin_amdgcn_mfma_f32_16x16x32_bf16(af, bf, acc1[t], 0, 0, 0);
        }
    }
    #pragma unroll
    for (int t = 0; t < 4; ++t)
        #pragma unroll
        for (int r = 0; r < 4; ++r) {
            float v = fmaxf(acc1[t][r], 0.0f);
            hw[(quad * 4 + r) * HS + fbase + t * 16 + m] = (short)f2bf(v);
        }
    __syncthreads();
    f32x4 acc2[4];
    #pragma unroll
    for (int t = 0; t < 4; ++t) {
        float bv = b2[fbase + t * 16 + m];
        acc2[t] = (f32x4){bv, bv, bv, bv};
    }
    #pragma unroll
    for (int s_ = 0; s_ < 4; ++s_) {
        int k0 = s_ * 32 + quad * 8;
        bf8_t af = *(const bf8_t*)(hw + m * HS + k0);
        #pragma unroll
        for (int t = 0; t < 4; ++t) {
            bf8_t bf = *(const bf8_t*)(wt2 + (size_t)(fbase + t * 16 + m) * HID + k0);
            acc2[t] = __builtin_amdgcn_mfma_f32_16x16x32_bf16(af, bf, acc2[t], 0, 0, 0);
        }
    }
    #pragma unroll
    for (int t = 0; t < 4; ++t)
        #pragma unroll
        for (int r = 0; r < 4; ++r) {
            int node = nb + quad * 4 + r;
            if (node < N_NODES) Hb[(size_t)node * HID + fbase + t * 16 + m] = f2bf(acc2[t][r]);
        }
    int blast = nb + 15 < N_NODES ? batch[nb + 15] : -1;
    int g0 = batch[nb < N_NODES ? nb : N_NODES - 1];
    if (nb + 15 < N_NODES && g0 == blast) {
        #pragma unroll
        for (int t = 0; t < 4; ++t) {
            float s = 0.0f, q = 0.0f;
            #pragma unroll
            for (int r = 0; r < 4; ++r) { float v = acc2[t][r]; s += v; q += v * v; }
            s += __shfl_xor(s, 16); q += __shfl_xor(q, 16);
            s += __shfl_xor(s, 32); q += __shfl_xor(q, 32);
            if (quad == 0) {
                atomicAdd(&gsum[g0 * HID + fbase + t * 16 + m], s);
                atomicAdd(&gsq[g0 * HID + fbase + t * 16 + m], q);
            }
        }
    } else {
        #pragma unroll
        for (int t = 0; t < 4; ++t)
            #pragma unroll
            for (int r = 0; r < 4; ++r) {
                int node = nb + quad * 4 + r;
                if (node < N_NODES) {
                    int g = batch[node];
                    float v = acc2[t][r];
                    atomicAdd(&gsum[g * HID + fbase + t * 16 + m], v);
                    atomicAdd(&gsq[g * HID + fbase + t * 16 + m], v * v);
                }
            }
    }
}

// ==================== normalize v2: vectorized short8 loads, LDS repack, bf8 stores ====================
#define NORM_N 16
__global__ __launch_bounds__(256) void k_norm(
    const unsigned short* __restrict__ Hb, const int* __restrict__ batch,
    const float* __restrict__ gsum, const float* __restrict__ gsq,
    const float* __restrict__ cnt,
    const float* __restrict__ gw, const float* __restrict__ gb,
    const float* __restrict__ gms,
    unsigned short* __restrict__ Hbp, float* __restrict__ pool, int accumulate) {
    __shared__ float ssc[HID];
    __shared__ float sof[HID];
    __shared__ float lp[HID];
    __shared__ short rp[NORM_N][HID];
    int n0 = blockIdx.x * NORM_N;
    int t = threadIdx.x;
    int nl = t >> 4, c = t & 15;
    int n = n0 + nl;
    int g0 = batch[n0], gN = batch[n0 + NORM_N - 1];
    if (g0 == gN) {
        if (t < HID) {
            float cg = fmaxf(cnt[g0], 1.0f);
            float mean = gsum[g0 * HID + t] / cg;
            float msq  = gsq[g0 * HID + t] / cg;
            float ms = gms[t];
            float var = fmaxf(msq - mean * mean * ms * (2.0f - ms), 0.0f);
            float s = gw[t] * rsqrtf(var + EPS);
            ssc[t] = s;
            sof[t] = gb[t] - s * mean * ms;
            lp[t] = 0.0f;
        }
        __syncthreads();
        bf8_t hv = *(const bf8_t*)(Hb + (size_t)n * HID + c * 8);
        #pragma unroll
        for (int j = 0; j < 8; ++j) {
            int f = c * 8 + j;
            float v = fmaxf(bf2f((unsigned short)hv[j]) * ssc[f] + sof[f], 0.0f);
            rp[nl][(f & 15) * 8 + (f >> 4)] = (short)f2bf(v);
            if (accumulate) atomicAdd(&lp[f], v);
        }
        __syncthreads();
        *(bf8_t*)(Hbp + (size_t)n * HID + c * 8) = *(bf8_t*)&rp[nl][c * 8];
        if (accumulate && t < HID) atomicAdd(&pool[g0 * HID + t], lp[t]);
    } else {
        int g = batch[n];
        float cg = fmaxf(cnt[g], 1.0f);
        bf8_t hv = *(const bf8_t*)(Hb + (size_t)n * HID + c * 8);
        #pragma unroll
        for (int j = 0; j < 8; ++j) {
            int f = c * 8 + j;
            float mean = gsum[g * HID + f] / cg;
            float msq  = gsq[g * HID + f] / cg;
            float ms = gms[f];
            float var = fmaxf(msq - mean * mean * ms * (2.0f - ms), 0.0f);
            float s = gw[f] * rsqrtf(var + EPS);
            float v = fmaxf(bf2f((unsigned short)hv[j]) * s + (gb[f] - s * mean * ms), 0.0f);
            rp[nl][(f & 15) * 8 + (f >> 4)] = (short)f2bf(v);
            if (accumulate) atomicAdd(&pool[g * HID + f], v);
        }
        __syncthreads();
        *(bf8_t*)(Hbp + (size_t)n * HID + c * 8) = *(bf8_t*)&rp[nl][c * 8];
    }
}

// ==================== output head ====================
__global__ __launch_bounds__(HID) void k_head(
    const float* __restrict__ pool,
    const float* __restrict__ fw1, const float* __restrict__ fb1,
    const float* __restrict__ fw2, const float* __restrict__ fb2,
    float* __restrict__ out) {
    __shared__ float ps[HID];
    __shared__ float red[2];
    int g = blockIdx.x;
    int t = threadIdx.x;
    ps[t] = pool[g * HID + t];
    __syncthreads();
    float acc = fb1[t];
    #pragma unroll 4
    for (int k = 0; k < HID; ++k) acc = fmaf(ps[k], fw1[k * HID + t], acc);
    float p = fmaxf(acc, 0.0f) * fw2[t];
    #pragma unroll
    for (int off = 32; off > 0; off >>= 1) p += __shfl_down(p, off, 64);
    if ((t & 63) == 0) red[t >> 6] = p;
    __syncthreads();
    if (t == 0) out[g] = red[0] + red[1] + fb2[0];
}

extern "C" void kernel_launch(void* const* d_in, const int* in_sizes, int n_in,
                              void* d_out, int out_size, void* d_ws, size_t ws_size,
                              hipStream_t stream) {
    const float* x     = (const float*)d_in[0];
    const int*   ei    = (const int*)d_in[1];
    const float* ea    = (const float*)d_in[2];
    const int*   batch = (const int*)d_in[3];
    const float* lw1 = (const float*)d_in[4];
    const float* lb1 = (const float*)d_in[5];
    const float* lw2 = (const float*)d_in[6];
    const float* lb2 = (const float*)d_in[7];
    const float* pw1 = (const float*)d_in[8];
    const float* pb1 = (const float*)d_in[9];
    const float* pw2 = (const float*)d_in[10];
    const float* pb2 = (const float*)d_in[11];
    const float* ew  = (const float*)d_in[12];
    const float* eb  = (const float*)d_in[13];
    const float* nw1 = (const float*)d_in[14];
    const float* nb1 = (const float*)d_in[15];
    const float* nw2 = (const float*)d_in[16];
    const float* nb2 = (const float*)d_in[17];
    const float* gw  = (const float*)d_in[18];
    const float* gb  = (const float*)d_in[19];
    const float* gms = (const float*)d_in[20];
    const float* fw1 = (const float*)d_in[21];
    const float* fb1 = (const float*)d_in[22];
    const float* fw2 = (const float*)d_in[23];
    const float* fb2 = (const float*)d_in[24];
    float* out = (float*)d_out;

    float* ws   = (float*)d_ws;
    float* H    = ws;                          // 12.8MB: bf16 Hb
    float* A    = H    + (size_t)N_NODES * HID;// 25.6MB: Abp bf16 (lower) + bkt (upper)
    float* gsum = A    + (size_t)N_NODES * HID;// 3 * NGRAPH*HID (per-layer)
    float* gsq  = gsum + NLAYERS * NGRAPH * HID;
    float* pool = gsq  + NLAYERS * NGRAPH * HID;
    float* cnt  = pool + NGRAPH * HID;         // 128 f
    int* bcnt_pad  = (int*)(cnt + NGRAPH);     // NB*16 = 6256 ints (padded counters)
    int* boff      = bcnt_pad + NB * 16;       // NB+1
    int* row_start = boff + 512;               // 50000
    int* row_end   = row_start + N_NODES;      // 50000
    int* csr_src   = row_end + N_NODES;        // 800000 (CSR-ordered src, 4B)
    unsigned short* cea  = (unsigned short*)(csr_src + N_EDGES);    // 12,800,000 bf16 (CSR order)
    unsigned short* wt   = cea + (size_t)N_EDGES * EDGE_DIM;        // 98304
    unsigned short* wenc = wt + NLAYERS * 2 * HID * HID;            // 49152
    unsigned short* wte  = wenc + 49152;                            // 12288
    unsigned short* Hbp  = wte + NLAYERS * 8 * 64 * 8;              // 6,400,000 bf16 (12.8 MB)
    unsigned short* Hb   = (unsigned short*)H;                      // 12.8 MB
    unsigned short* Abp  = (unsigned short*)A;                      // 12.8 MB
    int2* bkt    = (int2*)(Abp + (size_t)N_NODES * HID);            // NB*BCAP*8B = 12.7 MB (A upper)

    const int* srcs = ei;
    const int* dsts = ei + N_EDGES;

    // ---- init + bucket CSR build (+fused attr reorder) + weight conversion ----
    k_init<<<(NLAYERS * NGRAPH * HID + 255) / 256, 256, 0, stream>>>(
        bcnt_pad, pool, gsum, gsq, batch, cnt);
    k_wall<<<(159744 + 255) / 256, 256, 0, stream>>>(
        nw1, nw2, lw1, pw1, lw2, pw2, ew, eb, wt, wenc, wte);
    k_bfill<<<(N_EDGES + 255) / 256, 256, 0, stream>>>(srcs, dsts, bcnt_pad, bkt);
    k_bscan<<<1, 512, 0, stream>>>(bcnt_pad, boff);
    k_bcsr<<<NB, 256, 0, stream>>>(bcnt_pad, boff, bkt, ea,
                                   row_start, row_end, csr_src, cea);

    // ---- encoder (MFMA, role-split waves) -> Hbp ----
    k_encoder_mfma<<<(N_NODES + 31) / 32, 256, 0, stream>>>(
        x, wenc, lb1, lb2, pb1, pb2, Hbp);

    // ---- layers: gather, MLP, norm (stats inline) ----
    int mlp_blocks = (N_NODES + MLP_NODES_PER_BLOCK - 1) / MLP_NODES_PER_BLOCK;
    for (int l = 0; l < NLAYERS; ++l) {
        k_gather<<<N_NODES / 2, 256, 0, stream>>>(
            csr_src, cea, row_start, row_end,
            wte + (size_t)l * 4096, Hbp, Abp);
        k_mlp_mfma<<<mlp_blocks, 256, 0, stream>>>(
            Abp, batch,
            wt + (size_t)l * 2 * HID * HID,
            wt + (size_t)l * 2 * HID * HID + HID * HID,
            nb1 + l * HID, nb2 + l * HID,
            Hb, gsum + (size_t)l * NGRAPH * HID, gsq + (size_t)l * NGRAPH * HID);
        k_norm<<<N_NODES / NORM_N, 256, 0, stream>>>(
            Hb, batch,
            gsum + (size_t)l * NGRAPH * HID, gsq + (size_t)l * NGRAPH * HID,
            cnt, gw + l * HID, gb + l * HID, gms + l * HID,
            Hbp, pool, (l == NLAYERS - 1) ? 1 : 0);
    }
    k_head<<<NGRAPH, HID, 0, stream>>>(pool, fw1, fb1, fw2, fb2, out);
}

// Round 13
// 644.897 us; speedup vs baseline: 1.0168x; 1.0168x over previous
//
#include <hip/hip_runtime.h>

#define N_NODES 50000
#define N_EDGES 800000
#define IN_DIM  64
#define EDGE_DIM 16
#define HID     128
#define NLAYERS 3
#define NGRAPH  128
#define EPS     1e-5f

#define BSHIFT  7
#define NB      391        // ceil(50000/128)
#define BCAP    4064       // bucket capacity (mean 2048, sd ~45)

typedef __attribute__((ext_vector_type(8))) short bf8_t;
typedef __attribute__((ext_vector_type(4))) short bf4_t;
typedef __attribute__((ext_vector_type(4))) float f32x4;

__device__ __forceinline__ unsigned short f2bf(float x) {
    unsigned u = __float_as_uint(x);
    unsigned r = u + 0x7fffu + ((u >> 16) & 1u);   // round-to-nearest-even
    return (unsigned short)(r >> 16);
}
__device__ __forceinline__ float bf2f(unsigned short v) {
    return __uint_as_float(((unsigned)v) << 16);
}

// ==================== init (+ per-graph counts in block 0) ====================
__global__ void k_init(int* __restrict__ bcnt_pad, float* __restrict__ pool,
                       float* __restrict__ gsum, float* __restrict__ gsq,
                       const int* __restrict__ batch, float* __restrict__ cnt) {
    int i = blockIdx.x * blockDim.x + threadIdx.x;
    if (i < NB * 16) bcnt_pad[i] = 0;
    if (i < NGRAPH * HID) pool[i] = 0.0f;
    if (i < NLAYERS * NGRAPH * HID) { gsum[i] = 0.0f; gsq[i] = 0.0f; }
    if (blockIdx.x == 0 && threadIdx.x < NGRAPH) {
        int g = threadIdx.x;
        int lo = 0, hi = N_NODES;
        while (lo < hi) { int mid = (lo + hi) >> 1; if (batch[mid] < g) lo = mid + 1; else hi = mid; }
        int a = lo;
        lo = 0; hi = N_NODES;
        while (lo < hi) { int mid = (lo + hi) >> 1; if (batch[mid] < g + 1) lo = mid + 1; else hi = mid; }
        cnt[g] = (float)(lo - a);
    }
}

// ==================== all weight conversions in one kernel ====================
// [0,98304): nn wt ; [98304,147456): encoder ; [147456,159744): edge wte
__global__ void k_wall(const float* __restrict__ nw1, const float* __restrict__ nw2,
                       const float* __restrict__ lw1, const float* __restrict__ pw1,
                       const float* __restrict__ lw2, const float* __restrict__ pw2,
                       const float* __restrict__ ew, const float* __restrict__ eb,
                       unsigned short* __restrict__ wt,
                       unsigned short* __restrict__ we,
                       unsigned short* __restrict__ wte) {
    int idx = blockIdx.x * 256 + threadIdx.x;
    if (idx < 98304) {
        int k = idx & 127;
        int n = (idx >> 7) & 127;
        int which = (idx >> 14) & 1;
        int l = idx >> 15;
        const float* w = (which == 0 ? nw1 : nw2) + l * HID * HID;
        wt[idx] = f2bf(w[k * HID + n]);
    } else if (idx < 147456) {
        int r0 = idx - 98304;
        float v;
        if (r0 < 8192)       { int n = r0 >> 6, k = r0 & 63;            v = lw1[k * HID + n]; }
        else if (r0 < 16384) { int r = r0 - 8192;  int n = r >> 6, k = r & 63;  v = pw1[k * HID + n]; }
        else if (r0 < 32768) { int r = r0 - 16384; int n = r >> 7, k = r & 127; v = lw2[k * HID + n]; }
        else                 { int r = r0 - 32768; int n = r >> 7, k = r & 127; v = pw2[k * HID + n]; }
        we[r0] = f2bf(v);
    } else if (idx < 159744) {
        int r0 = idx - 147456;
        int j = r0 & 7;
        int lane = (r0 >> 3) & 63;
        int t = (r0 >> 9) & 7;
        int l = r0 >> 12;
        int k = (lane >> 4) * 8 + j;
        int feat = t * 16 + (lane & 15);
        float v = 0.0f;
        if (k < EDGE_DIM)       v = ew[l * EDGE_DIM * HID + k * HID + feat];
        else if (k == EDGE_DIM) v = eb[l * HID + feat];
        wte[r0] = f2bf(v);
    }
}

// ==================== bucket scatter: edge -> bucket (dst>>7), packed {src, dl<<20|eid} ====================
__global__ void k_bfill(const int* __restrict__ srcs, const int* __restrict__ dsts,
                        int* __restrict__ bcnt_pad, int2* __restrict__ bkt) {
    int e = blockIdx.x * blockDim.x + threadIdx.x;
    if (e < N_EDGES) {
        int d = dsts[e];
        int b = d >> BSHIFT;
        int pos = atomicAdd(&bcnt_pad[b * 16], 1);
        if (pos < BCAP)
            bkt[(size_t)b * BCAP + pos] = make_int2(srcs[e], ((d & 127) << 20) | e);
    }
}

// ==================== scan bucket counts -> boff ====================
__global__ __launch_bounds__(512) void k_bscan(const int* __restrict__ bcnt_pad,
                                               int* __restrict__ boff) {
    __shared__ int s[512];
    int t = threadIdx.x;
    int v = (t < NB) ? bcnt_pad[t * 16] : 0;
    s[t] = v; __syncthreads();
    for (int off = 1; off < 512; off <<= 1) {
        int x = (t >= off) ? s[t - off] : 0;
        __syncthreads();
        s[t] += x;
        __syncthreads();
    }
    if (t < NB) boff[t] = s[t] - v;
    if (t == NB - 1) boff[NB] = s[t];
}

// ==================== per-bucket CSR build: local hist+scan -> row bounds + csr_se ====================
__global__ __launch_bounds__(256) void k_bcsr(const int* __restrict__ bcnt_pad,
                                              const int* __restrict__ boff,
                                              const int2* __restrict__ bkt,
                                              int* __restrict__ row_start,
                                              int* __restrict__ row_end,
                                              int2* __restrict__ csr_se) {
    __shared__ int lcnt[128];
    __shared__ int lsc[128];
    __shared__ int lfill[128];
    int b = blockIdx.x, t = threadIdx.x;
    int base = boff[b];
    int ecnt = bcnt_pad[b * 16]; if (ecnt > BCAP) ecnt = BCAP;
    if (t < 128) lcnt[t] = 0;
    __syncthreads();
    for (int i = t; i < ecnt; i += 256) {
        int2 en = bkt[(size_t)b * BCAP + i];
        atomicAdd(&lcnt[(en.y >> 20) & 127], 1);
    }
    __syncthreads();
    if (t < 128) lsc[t] = lcnt[t];
    __syncthreads();
    for (int off = 1; off < 128; off <<= 1) {
        int x = (t < 128 && t >= off) ? lsc[t - off] : 0;
        __syncthreads();
        if (t < 128) lsc[t] += x;
        __syncthreads();
    }
    if (t < 128) {
        int excl = lsc[t] - lcnt[t];
        lfill[t] = excl;
        int node = (b << BSHIFT) + t;
        if (node < N_NODES) {
            row_start[node] = base + excl;
            row_end[node]   = base + excl + lcnt[t];
        }
    }
    __syncthreads();
    for (int i = t; i < ecnt; i += 256) {
        int2 en = bkt[(size_t)b * BCAP + i];
        int q = atomicAdd(&lfill[(en.y >> 20) & 127], 1);
        csr_se[base + q] = make_int2(en.x, en.y & 0xFFFFF);
    }
}

// ==================== reorder: gather ea[eid] (64B-aligned lines) -> CSR-ordered bf16 ====================
__global__ __launch_bounds__(256) void k_reorder(const int2* __restrict__ csr_se,
                                                 const float* __restrict__ ea,
                                                 int* __restrict__ csr_src,
                                                 unsigned short* __restrict__ cea) {
    int p = blockIdx.x * blockDim.x + threadIdx.x;
    if (p < N_EDGES) {
        int2 se = csr_se[p];
        csr_src[p] = se.x;
        const float* s = ea + (size_t)se.y * EDGE_DIM;
        float4 a0 = *(const float4*)(s);
        float4 a1 = *(const float4*)(s + 4);
        float4 a2 = *(const float4*)(s + 8);
        float4 a3 = *(const float4*)(s + 12);
        bf8_t v0, v1;
        v0[0] = (short)f2bf(a0.x); v0[1] = (short)f2bf(a0.y);
        v0[2] = (short)f2bf(a0.z); v0[3] = (short)f2bf(a0.w);
        v0[4] = (short)f2bf(a1.x); v0[5] = (short)f2bf(a1.y);
        v0[6] = (short)f2bf(a1.z); v0[7] = (short)f2bf(a1.w);
        v1[0] = (short)f2bf(a2.x); v1[1] = (short)f2bf(a2.y);
        v1[2] = (short)f2bf(a2.z); v1[3] = (short)f2bf(a2.w);
        v1[4] = (short)f2bf(a3.x); v1[5] = (short)f2bf(a3.y);
        v1[6] = (short)f2bf(a3.z); v1[7] = (short)f2bf(a3.w);
        *(bf8_t*)(cea + (size_t)p * EDGE_DIM) = v0;
        *(bf8_t*)(cea + (size_t)p * EDGE_DIM + 8) = v1;
    }
}

// ==================== encoder v2: role-split waves (lig XOR prot per wave) ====================
#define HS 136   // LDS row stride in shorts
__global__ __launch_bounds__(256, 8) void k_encoder_mfma(
    const float* __restrict__ x,
    const unsigned short* __restrict__ we,
    const float* __restrict__ lb1, const float* __restrict__ lb2,
    const float* __restrict__ pb1, const float* __restrict__ pb2,
    unsigned short* __restrict__ Hbp) {
    __shared__ short h1s[4][16 * HS];
    int w = threadIdx.x >> 6, lane = threadIdx.x & 63;
    int m = lane & 15, quad = lane >> 4;
    int tile = w >> 1, role = w & 1;
    int nb = blockIdx.x * 32 + tile * 16;
    short* hl = h1s[w];
    int nclamp = nb + m; if (nclamp >= N_NODES) nclamp = N_NODES - 1;
    const float* xp = x + (size_t)nclamp * IN_DIM;
    const float* b1 = role ? pb1 : lb1;
    const float* b2 = role ? pb2 : lb2;
    const unsigned short* w1 = we + role * 8192;
    const unsigned short* w2 = we + 16384 + role * 16384;

    f32x4 a1[8];
    #pragma unroll
    for (int t = 0; t < 8; ++t) {
        float bv = b1[t * 16 + m];
        a1[t] = (f32x4){bv, bv, bv, bv};
    }
    #pragma unroll
    for (int s_ = 0; s_ < 2; ++s_) {
        int k0 = s_ * 32 + quad * 8;
        float4 a0 = *(const float4*)(xp + k0);
        float4 a1v = *(const float4*)(xp + k0 + 4);
        bf8_t af;
        af[0] = (short)f2bf(a0.x); af[1] = (short)f2bf(a0.y);
        af[2] = (short)f2bf(a0.z); af[3] = (short)f2bf(a0.w);
        af[4] = (short)f2bf(a1v.x); af[5] = (short)f2bf(a1v.y);
        af[6] = (short)f2bf(a1v.z); af[7] = (short)f2bf(a1v.w);
        #pragma unroll
        for (int t = 0; t < 8; ++t) {
            bf8_t bw = *(const bf8_t*)(w1 + (t * 16 + m) * 64 + k0);
            a1[t] = __builtin_amdgcn_mfma_f32_16x16x32_bf16(af, bw, a1[t], 0, 0, 0);
        }
    }
    #pragma unroll
    for (int t = 0; t < 8; ++t)
        #pragma unroll
        for (int r = 0; r < 4; ++r)
            hl[(quad * 4 + r) * HS + t * 16 + m] = (short)f2bf(fmaxf(a1[t][r], 0.0f));
    __syncthreads();
    f32x4 a2[8];
    #pragma unroll
    for (int t = 0; t < 8; ++t) {
        float bv = b2[t * 16 + m];
        a2[t] = (f32x4){bv, bv, bv, bv};
    }
    #pragma unroll
    for (int s_ = 0; s_ < 4; ++s_) {
        int k0 = s_ * 32 + quad * 8;
        bf8_t af = *(const bf8_t*)(hl + m * HS + k0);
        #pragma unroll
        for (int t = 0; t < 8; ++t) {
            bf8_t bw = *(const bf8_t*)(w2 + (t * 16 + m) * 128 + k0);
            a2[t] = __builtin_amdgcn_mfma_f32_16x16x32_bf16(af, bw, a2[t], 0, 0, 0);
        }
    }
    #pragma unroll
    for (int r = 0; r < 4; ++r) {
        int node = nb + quad * 4 + r;
        if (node < N_NODES) {
            bool prot = x[(size_t)node * IN_DIM + (IN_DIM - 1)] > 0.5f;
            if (prot == (role == 1)) {
                bf8_t o;
                #pragma unroll
                for (int t = 0; t < 8; ++t)
                    o[t] = (short)f2bf(fmaxf(a2[t][r], 0.0f));
                *(bf8_t*)(Hbp + (size_t)node * HID + m * 8) = o;
            }
        }
    }
}

// ==================== edge gather v9 (proven 57us / 131MB floor) ====================
// Each 64-lane wave handles ONE node and HALF (64) of the output features.
// eb folded into wte k==16 row via af[0]=1.0 at quad==2.
__global__ __launch_bounds__(256, 8) void k_gather(
    const int* __restrict__ csr_src, const unsigned short* __restrict__ cea,
    const int* __restrict__ row_start, const int* __restrict__ row_end,
    const unsigned short* __restrict__ wte,
    const unsigned short* __restrict__ Hbp, unsigned short* __restrict__ Abp) {
    int w = threadIdx.x >> 6, lane = threadIdx.x & 63;
    int m = lane & 15, quad = lane >> 4;
    int n = blockIdx.x * 2 + (w >> 1);
    int half = w & 1;

    bf8_t bw[4];
    #pragma unroll
    for (int t = 0; t < 4; ++t)
        bw[t] = *(const bf8_t*)(wte + ((size_t)(half * 4 + t) * 64 + lane) * 8);

    float acc[4];
    #pragma unroll
    for (int t = 0; t < 4; ++t) acc[t] = 0.0f;

    int p  = __builtin_amdgcn_readfirstlane(row_start[n]);
    int pe = __builtin_amdgcn_readfirstlane(row_end[n]);

    const f32x4 zc = (f32x4){0.0f, 0.0f, 0.0f, 0.0f};

    for (; p + 16 <= pe; p += 16) {
        bf8_t af = (bf8_t){0, 0, 0, 0, 0, 0, 0, 0};
        if (quad < 2)
            af = *(const bf8_t*)(cea + (size_t)(p + m) * EDGE_DIM + quad * 8);
        else if (quad == 2)
            af[0] = (short)0x3F80;   // 1.0 bf16 -> multiplies eb row (k==16)
        int sr[4];
        #pragma unroll
        for (int r = 0; r < 4; ++r) sr[r] = csr_src[p + quad * 4 + r];
        bf4_t hrow[4];
        #pragma unroll
        for (int r = 0; r < 4; ++r)
            hrow[r] = *(const bf4_t*)(Hbp + (size_t)sr[r] * HID + m * 8 + half * 4);
        f32x4 d[4];
        #pragma unroll
        for (int t = 0; t < 4; ++t)
            d[t] = __builtin_amdgcn_mfma_f32_16x16x32_bf16(af, bw[t], zc, 0, 0, 0);
        #pragma unroll
        for (int t = 0; t < 4; ++t)
            #pragma unroll
            for (int r = 0; r < 4; ++r)
                acc[t] += fmaxf(bf2f((unsigned short)hrow[r][t]) + d[t][r], 0.0f);
    }
    int rem = pe - p;
    if (rem > 0) {
        bf8_t af = (bf8_t){0, 0, 0, 0, 0, 0, 0, 0};
        if (quad < 2 && m < rem)
            af = *(const bf8_t*)(cea + (size_t)(p + m) * EDGE_DIM + quad * 8);
        else if (quad == 2)
            af[0] = (short)0x3F80;
        int sr[4];
        #pragma unroll
        for (int r = 0; r < 4; ++r) {
            int idx = p + quad * 4 + r; if (idx >= pe) idx = pe - 1;
            sr[r] = csr_src[idx];
        }
        bf4_t hrow[4];
        #pragma unroll
        for (int r = 0; r < 4; ++r)
            hrow[r] = *(const bf4_t*)(Hbp + (size_t)sr[r] * HID + m * 8 + half * 4);
        f32x4 d[4];
        #pragma unroll
        for (int t = 0; t < 4; ++t)
            d[t] = __builtin_amdgcn_mfma_f32_16x16x32_bf16(af, bw[t], zc, 0, 0, 0);
        #pragma unroll
        for (int t = 0; t < 4; ++t)
            #pragma unroll
            for (int r = 0; r < 4; ++r)
                if (quad * 4 + r < rem)
                    acc[t] += fmaxf(bf2f((unsigned short)hrow[r][t]) + d[t][r], 0.0f);
    }
    #pragma unroll
    for (int t = 0; t < 4; ++t) {
        acc[t] += __shfl_xor(acc[t], 16);
        acc[t] += __shfl_xor(acc[t], 32);
    }
    // lane (quad,m) writes feature (half*4+quad)*16 + m ; add self term from Hbp
    float asel = (quad == 0) ? acc[0] : (quad == 1) ? acc[1] : (quad == 2) ? acc[2] : acc[3];
    float self_ = bf2f(Hbp[(size_t)n * HID + m * 8 + half * 4 + quad]);
    Abp[(size_t)n * HID + (half * 4 + quad) * 16 + m] = f2bf(asel + self_);
}

// ==================== node MLP v2: feature-split wave pairs (A bf16 in, H bf16 out) ====================
// Wave pair (tile, role): role computes output features role*64..role*64+63 of BOTH
// layers for the pair's 16 nodes. Layer-1 halves meet in the shared LDS h1 tile.
#define MLP_NODES_PER_BLOCK 32
__global__ __launch_bounds__(256, 6) void k_mlp_mfma(
    const unsigned short* __restrict__ Abp, const int* __restrict__ batch,
    const unsigned short* __restrict__ wt1, const unsigned short* __restrict__ wt2,
    const float* __restrict__ b1, const float* __restrict__ b2,
    unsigned short* __restrict__ Hb, float* __restrict__ gsum, float* __restrict__ gsq) {
    __shared__ short h1s[2][16 * HS];
    int w = threadIdx.x >> 6;
    int lane = threadIdx.x & 63;
    int m = lane & 15;
    int quad = lane >> 4;
    int tile = w >> 1, role = w & 1;
    int nb = blockIdx.x * MLP_NODES_PER_BLOCK + tile * 16;
    short* hw = h1s[tile];
    int fbase = role * 64;

    int nclamp = nb + m; if (nclamp >= N_NODES) nclamp = N_NODES - 1;
    const unsigned short* Ap = Abp + (size_t)nclamp * HID;
    f32x4 acc1[4];
    #pragma unroll
    for (int t = 0; t < 4; ++t) {
        float bv = b1[fbase + t * 16 + m];
        acc1[t] = (f32x4){bv, bv, bv, bv};
    }
    #pragma unroll
    for (int s_ = 0; s_ < 4; ++s_) {
        int k0 = s_ * 32 + quad * 8;
        bf8_t af = *(const bf8_t*)(Ap + k0);
        #pragma unroll
        for (int t = 0; t < 4; ++t) {
            bf8_t bf = *(const bf8_t*)(wt1 + (size_t)(fbase + t * 16 + m) * HID + k0);
            acc1[t] = __builtin_amdgcn_mfma_f32_16x16x32_bf16(af, bf, acc1[t], 0, 0, 0);
        }
    }
    #pragma unroll
    for (int t = 0; t < 4; ++t)
        #pragma unroll
        for (int r = 0; r < 4; ++r) {
            float v = fmaxf(acc1[t][r], 0.0f);
            hw[(quad * 4 + r) * HS + fbase + t * 16 + m] = (short)f2bf(v);
        }
    __syncthreads();
    f32x4 acc2[4];
    #pragma unroll
    for (int t = 0; t < 4; ++t) {
        float bv = b2[fbase + t * 16 + m];
        acc2[t] = (f32x4){bv, bv, bv, bv};
    }
    #pragma unroll
    for (int s_ = 0; s_ < 4; ++s_) {
        int k0 = s_ * 32 + quad * 8;
        bf8_t af = *(const bf8_t*)(hw + m * HS + k0);
        #pragma unroll
        for (int t = 0; t < 4; ++t) {
            bf8_t bf = *(const bf8_t*)(wt2 + (size_t)(fbase + t * 16 + m) * HID + k0);
            acc2[t] = __builtin_amdgcn_mfma_f32_16x16x32_bf16(af, bf, acc2[t], 0, 0, 0);
        }
    }
    #pragma unroll
    for (int t = 0; t < 4; ++t)
        #pragma unroll
        for (int r = 0; r < 4; ++r) {
            int node = nb + quad * 4 + r;
            if (node < N_NODES) Hb[(size_t)node * HID + fbase + t * 16 + m] = f2bf(acc2[t][r]);
        }
    int blast = nb + 15 < N_NODES ? batch[nb + 15] : -1;
    int g0 = batch[nb < N_NODES ? nb : N_NODES - 1];
    if (nb + 15 < N_NODES && g0 == blast) {
        #pragma unroll
        for (int t = 0; t < 4; ++t) {
            float s = 0.0f, q = 0.0f;
            #pragma unroll
            for (int r = 0; r < 4; ++r) { float v = acc2[t][r]; s += v; q += v * v; }
            s += __shfl_xor(s, 16); q += __shfl_xor(q, 16);
            s += __shfl_xor(s, 32); q += __shfl_xor(q, 32);
            if (quad == 0) {
                atomicAdd(&gsum[g0 * HID + fbase + t * 16 + m], s);
                atomicAdd(&gsq[g0 * HID + fbase + t * 16 + m], q);
            }
        }
    } else {
        #pragma unroll
        for (int t = 0; t < 4; ++t)
            #pragma unroll
            for (int r = 0; r < 4; ++r) {
                int node = nb + quad * 4 + r;
                if (node < N_NODES) {
                    int g = batch[node];
                    float v = acc2[t][r];
                    atomicAdd(&gsum[g * HID + fbase + t * 16 + m], v);
                    atomicAdd(&gsq[g * HID + fbase + t * 16 + m], v * v);
                }
            }
    }
}

// ==================== normalize v2: vectorized short8 loads, LDS repack, bf8 stores ====================
#define NORM_N 16
__global__ __launch_bounds__(256) void k_norm(
    const unsigned short* __restrict__ Hb, const int* __restrict__ batch,
    const float* __restrict__ gsum, const float* __restrict__ gsq,
    const float* __restrict__ cnt,
    const float* __restrict__ gw, const float* __restrict__ gb,
    const float* __restrict__ gms,
    unsigned short* __restrict__ Hbp, float* __restrict__ pool, int accumulate) {
    __shared__ float ssc[HID];
    __shared__ float sof[HID];
    __shared__ float lp[HID];
    __shared__ short rp[NORM_N][HID];
    int n0 = blockIdx.x * NORM_N;
    int t = threadIdx.x;
    int nl = t >> 4, c = t & 15;
    int n = n0 + nl;
    int g0 = batch[n0], gN = batch[n0 + NORM_N - 1];
    if (g0 == gN) {
        if (t < HID) {
            float cg = fmaxf(cnt[g0], 1.0f);
            float mean = gsum[g0 * HID + t] / cg;
            float msq  = gsq[g0 * HID + t] / cg;
            float ms = gms[t];
            float var = fmaxf(msq - mean * mean * ms * (2.0f - ms), 0.0f);
            float s = gw[t] * rsqrtf(var + EPS);
            ssc[t] = s;
            sof[t] = gb[t] - s * mean * ms;
            lp[t] = 0.0f;
        }
        __syncthreads();
        bf8_t hv = *(const bf8_t*)(Hb + (size_t)n * HID + c * 8);
        #pragma unroll
        for (int j = 0; j < 8; ++j) {
            int f = c * 8 + j;
            float v = fmaxf(bf2f((unsigned short)hv[j]) * ssc[f] + sof[f], 0.0f);
            rp[nl][(f & 15) * 8 + (f >> 4)] = (short)f2bf(v);
            if (accumulate) atomicAdd(&lp[f], v);
        }
        __syncthreads();
        *(bf8_t*)(Hbp + (size_t)n * HID + c * 8) = *(bf8_t*)&rp[nl][c * 8];
        if (accumulate && t < HID) atomicAdd(&pool[g0 * HID + t], lp[t]);
    } else {
        int g = batch[n];
        float cg = fmaxf(cnt[g], 1.0f);
        bf8_t hv = *(const bf8_t*)(Hb + (size_t)n * HID + c * 8);
        #pragma unroll
        for (int j = 0; j < 8; ++j) {
            int f = c * 8 + j;
            float mean = gsum[g * HID + f] / cg;
            float msq  = gsq[g * HID + f] / cg;
            float ms = gms[f];
            float var = fmaxf(msq - mean * mean * ms * (2.0f - ms), 0.0f);
            float s = gw[f] * rsqrtf(var + EPS);
            float v = fmaxf(bf2f((unsigned short)hv[j]) * s + (gb[f] - s * mean * ms), 0.0f);
            rp[nl][(f & 15) * 8 + (f >> 4)] = (short)f2bf(v);
            if (accumulate) atomicAdd(&pool[g * HID + f], v);
        }
        __syncthreads();
        *(bf8_t*)(Hbp + (size_t)n * HID + c * 8) = *(bf8_t*)&rp[nl][c * 8];
    }
}

// ==================== output head ====================
__global__ __launch_bounds__(HID) void k_head(
    const float* __restrict__ pool,
    const float* __restrict__ fw1, const float* __restrict__ fb1,
    const float* __restrict__ fw2, const float* __restrict__ fb2,
    float* __restrict__ out) {
    __shared__ float ps[HID];
    __shared__ float red[2];
    int g = blockIdx.x;
    int t = threadIdx.x;
    ps[t] = pool[g * HID + t];
    __syncthreads();
    float acc = fb1[t];
    #pragma unroll 4
    for (int k = 0; k < HID; ++k) acc = fmaf(ps[k], fw1[k * HID + t], acc);
    float p = fmaxf(acc, 0.0f) * fw2[t];
    #pragma unroll
    for (int off = 32; off > 0; off >>= 1) p += __shfl_down(p, off, 64);
    if ((t & 63) == 0) red[t >> 6] = p;
    __syncthreads();
    if (t == 0) out[g] = red[0] + red[1] + fb2[0];
}

extern "C" void kernel_launch(void* const* d_in, const int* in_sizes, int n_in,
                              void* d_out, int out_size, void* d_ws, size_t ws_size,
                              hipStream_t stream) {
    const float* x     = (const float*)d_in[0];
    const int*   ei    = (const int*)d_in[1];
    const float* ea    = (const float*)d_in[2];
    const int*   batch = (const int*)d_in[3];
    const float* lw1 = (const float*)d_in[4];
    const float* lb1 = (const float*)d_in[5];
    const float* lw2 = (const float*)d_in[6];
    const float* lb2 = (const float*)d_in[7];
    const float* pw1 = (const float*)d_in[8];
    const float* pb1 = (const float*)d_in[9];
    const float* pw2 = (const float*)d_in[10];
    const float* pb2 = (const float*)d_in[11];
    const float* ew  = (const float*)d_in[12];
    const float* eb  = (const float*)d_in[13];
    const float* nw1 = (const float*)d_in[14];
    const float* nb1 = (const float*)d_in[15];
    const float* nw2 = (const float*)d_in[16];
    const float* nb2 = (const float*)d_in[17];
    const float* gw  = (const float*)d_in[18];
    const float* gb  = (const float*)d_in[19];
    const float* gms = (const float*)d_in[20];
    const float* fw1 = (const float*)d_in[21];
    const float* fb1 = (const float*)d_in[22];
    const float* fw2 = (const float*)d_in[23];
    const float* fb2 = (const float*)d_in[24];
    float* out = (float*)d_out;

    float* ws   = (float*)d_ws;
    float* H    = ws;                          // 12.8MB: bf16 Hb / csr_se staging (dead until layers)
    float* A    = H    + (size_t)N_NODES * HID;// 25.6MB: Abp bf16 (lower) + bkt (upper)
    float* gsum = A    + (size_t)N_NODES * HID;// 3 * NGRAPH*HID (per-layer)
    float* gsq  = gsum + NLAYERS * NGRAPH * HID;
    float* pool = gsq  + NLAYERS * NGRAPH * HID;
    float* cnt  = pool + NGRAPH * HID;         // 128 f
    int* bcnt_pad  = (int*)(cnt + NGRAPH);     // NB*16 = 6256 ints (padded counters)
    int* boff      = bcnt_pad + NB * 16;       // NB+1
    int* row_start = boff + 512;               // 50000
    int* row_end   = row_start + N_NODES;      // 50000
    int* csr_src   = row_end + N_NODES;        // 800000 (CSR-ordered src, 4B)
    unsigned short* cea  = (unsigned short*)(csr_src + N_EDGES);    // 12,800,000 bf16 (CSR order)
    unsigned short* wt   = cea + (size_t)N_EDGES * EDGE_DIM;        // 98304
    unsigned short* wenc = wt + NLAYERS * 2 * HID * HID;            // 49152
    unsigned short* wte  = wenc + 49152;                            // 12288
    unsigned short* Hbp  = wte + NLAYERS * 8 * 64 * 8;              // 6,400,000 bf16 (12.8 MB)
    unsigned short* Hb   = (unsigned short*)H;                      // 12.8 MB
    unsigned short* Abp  = (unsigned short*)A;                      // 12.8 MB
    int2* bkt    = (int2*)(Abp + (size_t)N_NODES * HID);            // NB*BCAP*8B = 12.7 MB (A upper)
    int2* csr_se = (int2*)H;                                        // 6.4 MB staging in H region

    const int* srcs = ei;
    const int* dsts = ei + N_EDGES;

    // ---- init + bucket CSR build + weight conversion ----
    k_init<<<(NLAYERS * NGRAPH * HID + 255) / 256, 256, 0, stream>>>(
        bcnt_pad, pool, gsum, gsq, batch, cnt);
    k_wall<<<(159744 + 255) / 256, 256, 0, stream>>>(
        nw1, nw2, lw1, pw1, lw2, pw2, ew, eb, wt, wenc, wte);
    k_bfill<<<(N_EDGES + 255) / 256, 256, 0, stream>>>(srcs, dsts, bcnt_pad, bkt);
    k_bscan<<<1, 512, 0, stream>>>(bcnt_pad, boff);
    k_bcsr<<<NB, 256, 0, stream>>>(bcnt_pad, boff, bkt, row_start, row_end, csr_se);
    k_reorder<<<(N_EDGES + 255) / 256, 256, 0, stream>>>(csr_se, ea, csr_src, cea);

    // ---- encoder (MFMA, role-split waves) -> Hbp ----
    k_encoder_mfma<<<(N_NODES + 31) / 32, 256, 0, stream>>>(
        x, wenc, lb1, lb2, pb1, pb2, Hbp);

    // ---- layers: gather, MLP, norm (stats inline) ----
    int mlp_blocks = (N_NODES + MLP_NODES_PER_BLOCK - 1) / MLP_NODES_PER_BLOCK;
    for (int l = 0; l < NLAYERS; ++l) {
        k_gather<<<N_NODES / 2, 256, 0, stream>>>(
            csr_src, cea, row_start, row_end,
            wte + (size_t)l * 4096, Hbp, Abp);
        k_mlp_mfma<<<mlp_blocks, 256, 0, stream>>>(
            Abp, batch,
            wt + (size_t)l * 2 * HID * HID,
            wt + (size_t)l * 2 * HID * HID + HID * HID,
            nb1 + l * HID, nb2 + l * HID,
            Hb, gsum + (size_t)l * NGRAPH * HID, gsq + (size_t)l * NGRAPH * HID);
        k_norm<<<N_NODES / NORM_N, 256, 0, stream>>>(
            Hb, batch,
            gsum + (size_t)l * NGRAPH * HID, gsq + (size_t)l * NGRAPH * HID,
            cnt, gw + l * HID, gb + l * HID, gms + l * HID,
            Hbp, pool, (l == NLAYERS - 1) ? 1 : 0);
    }
    k_head<<<NGRAPH, HID, 0, stream>>>(pool, fw1, fb1, fw2, fb2, out);
}

// Round 14
// 608.927 us; speedup vs baseline: 1.0768x; 1.0591x over previous
//
#include <hip/hip_runtime.h>

#define N_NODES 50000
#define N_EDGES 800000
#define IN_DIM  64
#define EDGE_DIM 16
#define HID     128
#define NLAYERS 3
#define NGRAPH  128
#define EPS     1e-5f

#define BSHIFT  7
#define NB      391        // ceil(50000/128)
#define BCAP    4064       // bucket capacity (mean 2048, sd ~45)

typedef __attribute__((ext_vector_type(8))) short bf8_t;
typedef __attribute__((ext_vector_type(4))) short bf4_t;
typedef __attribute__((ext_vector_type(4))) float f32x4;

__device__ __forceinline__ unsigned short f2bf(float x) {
    unsigned u = __float_as_uint(x);
    unsigned r = u + 0x7fffu + ((u >> 16) & 1u);   // round-to-nearest-even
    return (unsigned short)(r >> 16);
}
__device__ __forceinline__ float bf2f(unsigned short v) {
    return __uint_as_float(((unsigned)v) << 16);
}

// ==================== init (+ per-graph counts in block 0) ====================
__global__ void k_init(int* __restrict__ bcnt_pad, float* __restrict__ pool,
                       float* __restrict__ gsum, float* __restrict__ gsq,
                       const int* __restrict__ batch, float* __restrict__ cnt) {
    int i = blockIdx.x * blockDim.x + threadIdx.x;
    if (i < NB * 16) bcnt_pad[i] = 0;
    if (i < NGRAPH * HID) pool[i] = 0.0f;
    if (i < NLAYERS * NGRAPH * HID) { gsum[i] = 0.0f; gsq[i] = 0.0f; }
    if (blockIdx.x == 0 && threadIdx.x < NGRAPH) {
        int g = threadIdx.x;
        int lo = 0, hi = N_NODES;
        while (lo < hi) { int mid = (lo + hi) >> 1; if (batch[mid] < g) lo = mid + 1; else hi = mid; }
        int a = lo;
        lo = 0; hi = N_NODES;
        while (lo < hi) { int mid = (lo + hi) >> 1; if (batch[mid] < g + 1) lo = mid + 1; else hi = mid; }
        cnt[g] = (float)(lo - a);
    }
}

// ==================== all weight conversions in one kernel ====================
// [0,98304): nn wt ; [98304,147456): encoder ; [147456,159744): edge wte
__global__ void k_wall(const float* __restrict__ nw1, const float* __restrict__ nw2,
                       const float* __restrict__ lw1, const float* __restrict__ pw1,
                       const float* __restrict__ lw2, const float* __restrict__ pw2,
                       const float* __restrict__ ew, const float* __restrict__ eb,
                       unsigned short* __restrict__ wt,
                       unsigned short* __restrict__ we,
                       unsigned short* __restrict__ wte) {
    int idx = blockIdx.x * 256 + threadIdx.x;
    if (idx < 98304) {
        int k = idx & 127;
        int n = (idx >> 7) & 127;
        int which = (idx >> 14) & 1;
        int l = idx >> 15;
        const float* w = (which == 0 ? nw1 : nw2) + l * HID * HID;
        wt[idx] = f2bf(w[k * HID + n]);
    } else if (idx < 147456) {
        int r0 = idx - 98304;
        float v;
        if (r0 < 8192)       { int n = r0 >> 6, k = r0 & 63;            v = lw1[k * HID + n]; }
        else if (r0 < 16384) { int r = r0 - 8192;  int n = r >> 6, k = r & 63;  v = pw1[k * HID + n]; }
        else if (r0 < 32768) { int r = r0 - 16384; int n = r >> 7, k = r & 127; v = lw2[k * HID + n]; }
        else                 { int r = r0 - 32768; int n = r >> 7, k = r & 127; v = pw2[k * HID + n]; }
        we[r0] = f2bf(v);
    } else if (idx < 159744) {
        int r0 = idx - 147456;
        int j = r0 & 7;
        int lane = (r0 >> 3) & 63;
        int t = (r0 >> 9) & 7;
        int l = r0 >> 12;
        int k = (lane >> 4) * 8 + j;
        int feat = t * 16 + (lane & 15);
        float v = 0.0f;
        if (k < EDGE_DIM)       v = ew[l * EDGE_DIM * HID + k * HID + feat];
        else if (k == EDGE_DIM) v = eb[l * HID + feat];
        wte[r0] = f2bf(v);
    }
}

// ==================== bucket scatter: edge -> bucket (dst>>7), packed {src, dl<<20|eid} ====================
__global__ void k_bfill(const int* __restrict__ srcs, const int* __restrict__ dsts,
                        int* __restrict__ bcnt_pad, int2* __restrict__ bkt) {
    int e = blockIdx.x * blockDim.x + threadIdx.x;
    if (e < N_EDGES) {
        int d = dsts[e];
        int b = d >> BSHIFT;
        int pos = atomicAdd(&bcnt_pad[b * 16], 1);
        if (pos < BCAP)
            bkt[(size_t)b * BCAP + pos] = make_int2(srcs[e], ((d & 127) << 20) | e);
    }
}

// ==================== scan bucket counts -> boff ====================
__global__ __launch_bounds__(512) void k_bscan(const int* __restrict__ bcnt_pad,
                                               int* __restrict__ boff) {
    __shared__ int s[512];
    int t = threadIdx.x;
    int v = (t < NB) ? bcnt_pad[t * 16] : 0;
    s[t] = v; __syncthreads();
    for (int off = 1; off < 512; off <<= 1) {
        int x = (t >= off) ? s[t - off] : 0;
        __syncthreads();
        s[t] += x;
        __syncthreads();
    }
    if (t < NB) boff[t] = s[t] - v;
    if (t == NB - 1) boff[NB] = s[t];
}

// ==================== per-bucket CSR build: local hist+scan -> row bounds + csr_se ====================
__global__ __launch_bounds__(256) void k_bcsr(const int* __restrict__ bcnt_pad,
                                              const int* __restrict__ boff,
                                              const int2* __restrict__ bkt,
                                              int* __restrict__ row_start,
                                              int* __restrict__ row_end,
                                              int2* __restrict__ csr_se) {
    __shared__ int lcnt[128];
    __shared__ int lsc[128];
    __shared__ int lfill[128];
    int b = blockIdx.x, t = threadIdx.x;
    int base = boff[b];
    int ecnt = bcnt_pad[b * 16]; if (ecnt > BCAP) ecnt = BCAP;
    if (t < 128) lcnt[t] = 0;
    __syncthreads();
    for (int i = t; i < ecnt; i += 256) {
        int2 en = bkt[(size_t)b * BCAP + i];
        atomicAdd(&lcnt[(en.y >> 20) & 127], 1);
    }
    __syncthreads();
    if (t < 128) lsc[t] = lcnt[t];
    __syncthreads();
    for (int off = 1; off < 128; off <<= 1) {
        int x = (t < 128 && t >= off) ? lsc[t - off] : 0;
        __syncthreads();
        if (t < 128) lsc[t] += x;
        __syncthreads();
    }
    if (t < 128) {
        int excl = lsc[t] - lcnt[t];
        lfill[t] = excl;
        int node = (b << BSHIFT) + t;
        if (node < N_NODES) {
            row_start[node] = base + excl;
            row_end[node]   = base + excl + lcnt[t];
        }
    }
    __syncthreads();
    for (int i = t; i < ecnt; i += 256) {
        int2 en = bkt[(size_t)b * BCAP + i];
        int q = atomicAdd(&lfill[(en.y >> 20) & 127], 1);
        csr_se[base + q] = make_int2(en.x, en.y & 0xFFFFF);
    }
}

// ==================== reorder: gather ea[eid] (64B-aligned lines) -> CSR-ordered bf16 ====================
__global__ __launch_bounds__(256) void k_reorder(const int2* __restrict__ csr_se,
                                                 const float* __restrict__ ea,
                                                 int* __restrict__ csr_src,
                                                 unsigned short* __restrict__ cea) {
    int p = blockIdx.x * blockDim.x + threadIdx.x;
    if (p < N_EDGES) {
        int2 se = csr_se[p];
        csr_src[p] = se.x;
        const float* s = ea + (size_t)se.y * EDGE_DIM;
        float4 a0 = *(const float4*)(s);
        float4 a1 = *(const float4*)(s + 4);
        float4 a2 = *(const float4*)(s + 8);
        float4 a3 = *(const float4*)(s + 12);
        bf8_t v0, v1;
        v0[0] = (short)f2bf(a0.x); v0[1] = (short)f2bf(a0.y);
        v0[2] = (short)f2bf(a0.z); v0[3] = (short)f2bf(a0.w);
        v0[4] = (short)f2bf(a1.x); v0[5] = (short)f2bf(a1.y);
        v0[6] = (short)f2bf(a1.z); v0[7] = (short)f2bf(a1.w);
        v1[0] = (short)f2bf(a2.x); v1[1] = (short)f2bf(a2.y);
        v1[2] = (short)f2bf(a2.z); v1[3] = (short)f2bf(a2.w);
        v1[4] = (short)f2bf(a3.x); v1[5] = (short)f2bf(a3.y);
        v1[6] = (short)f2bf(a3.z); v1[7] = (short)f2bf(a3.w);
        *(bf8_t*)(cea + (size_t)p * EDGE_DIM) = v0;
        *(bf8_t*)(cea + (size_t)p * EDGE_DIM + 8) = v1;
    }
}

// ==================== encoder v2: role-split waves (lig XOR prot per wave) ====================
#define HS 136   // LDS row stride in shorts
__global__ __launch_bounds__(256, 8) void k_encoder_mfma(
    const float* __restrict__ x,
    const unsigned short* __restrict__ we,
    const float* __restrict__ lb1, const float* __restrict__ lb2,
    const float* __restrict__ pb1, const float* __restrict__ pb2,
    unsigned short* __restrict__ Hbp) {
    __shared__ short h1s[4][16 * HS];
    int w = threadIdx.x >> 6, lane = threadIdx.x & 63;
    int m = lane & 15, quad = lane >> 4;
    int tile = w >> 1, role = w & 1;
    int nb = blockIdx.x * 32 + tile * 16;
    short* hl = h1s[w];
    int nclamp = nb + m; if (nclamp >= N_NODES) nclamp = N_NODES - 1;
    const float* xp = x + (size_t)nclamp * IN_DIM;
    const float* b1 = role ? pb1 : lb1;
    const float* b2 = role ? pb2 : lb2;
    const unsigned short* w1 = we + role * 8192;
    const unsigned short* w2 = we + 16384 + role * 16384;

    f32x4 a1[8];
    #pragma unroll
    for (int t = 0; t < 8; ++t) {
        float bv = b1[t * 16 + m];
        a1[t] = (f32x4){bv, bv, bv, bv};
    }
    #pragma unroll
    for (int s_ = 0; s_ < 2; ++s_) {
        int k0 = s_ * 32 + quad * 8;
        float4 a0 = *(const float4*)(xp + k0);
        float4 a1v = *(const float4*)(xp + k0 + 4);
        bf8_t af;
        af[0] = (short)f2bf(a0.x); af[1] = (short)f2bf(a0.y);
        af[2] = (short)f2bf(a0.z); af[3] = (short)f2bf(a0.w);
        af[4] = (short)f2bf(a1v.x); af[5] = (short)f2bf(a1v.y);
        af[6] = (short)f2bf(a1v.z); af[7] = (short)f2bf(a1v.w);
        #pragma unroll
        for (int t = 0; t < 8; ++t) {
            bf8_t bw = *(const bf8_t*)(w1 + (t * 16 + m) * 64 + k0);
            a1[t] = __builtin_amdgcn_mfma_f32_16x16x32_bf16(af, bw, a1[t], 0, 0, 0);
        }
    }
    #pragma unroll
    for (int t = 0; t < 8; ++t)
        #pragma unroll
        for (int r = 0; r < 4; ++r)
            hl[(quad * 4 + r) * HS + t * 16 + m] = (short)f2bf(fmaxf(a1[t][r], 0.0f));
    __syncthreads();
    f32x4 a2[8];
    #pragma unroll
    for (int t = 0; t < 8; ++t) {
        float bv = b2[t * 16 + m];
        a2[t] = (f32x4){bv, bv, bv, bv};
    }
    #pragma unroll
    for (int s_ = 0; s_ < 4; ++s_) {
        int k0 = s_ * 32 + quad * 8;
        bf8_t af = *(const bf8_t*)(hl + m * HS + k0);
        #pragma unroll
        for (int t = 0; t < 8; ++t) {
            bf8_t bw = *(const bf8_t*)(w2 + (t * 16 + m) * 128 + k0);
            a2[t] = __builtin_amdgcn_mfma_f32_16x16x32_bf16(af, bw, a2[t], 0, 0, 0);
        }
    }
    #pragma unroll
    for (int r = 0; r < 4; ++r) {
        int node = nb + quad * 4 + r;
        if (node < N_NODES) {
            bool prot = x[(size_t)node * IN_DIM + (IN_DIM - 1)] > 0.5f;
            if (prot == (role == 1)) {
                bf8_t o;
                #pragma unroll
                for (int t = 0; t < 8; ++t)
                    o[t] = (short)f2bf(fmaxf(a2[t][r], 0.0f));
                *(bf8_t*)(Hbp + (size_t)node * HID + m * 8) = o;
            }
        }
    }
}

// ==================== edge gather v9 (proven 57us / 131MB floor) ====================
// Each 64-lane wave handles ONE node and HALF (64) of the output features.
// eb folded into wte k==16 row via af[0]=1.0 at quad==2.
__global__ __launch_bounds__(256, 8) void k_gather(
    const int* __restrict__ csr_src, const unsigned short* __restrict__ cea,
    const int* __restrict__ row_start, const int* __restrict__ row_end,
    const unsigned short* __restrict__ wte,
    const unsigned short* __restrict__ Hbp, unsigned short* __restrict__ Abp) {
    int w = threadIdx.x >> 6, lane = threadIdx.x & 63;
    int m = lane & 15, quad = lane >> 4;
    int n = blockIdx.x * 2 + (w >> 1);
    int half = w & 1;

    bf8_t bw[4];
    #pragma unroll
    for (int t = 0; t < 4; ++t)
        bw[t] = *(const bf8_t*)(wte + ((size_t)(half * 4 + t) * 64 + lane) * 8);

    float acc[4];
    #pragma unroll
    for (int t = 0; t < 4; ++t) acc[t] = 0.0f;

    int p  = __builtin_amdgcn_readfirstlane(row_start[n]);
    int pe = __builtin_amdgcn_readfirstlane(row_end[n]);

    const f32x4 zc = (f32x4){0.0f, 0.0f, 0.0f, 0.0f};

    for (; p + 16 <= pe; p += 16) {
        bf8_t af = (bf8_t){0, 0, 0, 0, 0, 0, 0, 0};
        if (quad < 2)
            af = *(const bf8_t*)(cea + (size_t)(p + m) * EDGE_DIM + quad * 8);
        else if (quad == 2)
            af[0] = (short)0x3F80;   // 1.0 bf16 -> multiplies eb row (k==16)
        int sr[4];
        #pragma unroll
        for (int r = 0; r < 4; ++r) sr[r] = csr_src[p + quad * 4 + r];
        bf4_t hrow[4];
        #pragma unroll
        for (int r = 0; r < 4; ++r)
            hrow[r] = *(const bf4_t*)(Hbp + (size_t)sr[r] * HID + m * 8 + half * 4);
        f32x4 d[4];
        #pragma unroll
        for (int t = 0; t < 4; ++t)
            d[t] = __builtin_amdgcn_mfma_f32_16x16x32_bf16(af, bw[t], zc, 0, 0, 0);
        #pragma unroll
        for (int t = 0; t < 4; ++t)
            #pragma unroll
            for (int r = 0; r < 4; ++r)
                acc[t] += fmaxf(bf2f((unsigned short)hrow[r][t]) + d[t][r], 0.0f);
    }
    int rem = pe - p;
    if (rem > 0) {
        bf8_t af = (bf8_t){0, 0, 0, 0, 0, 0, 0, 0};
        if (quad < 2 && m < rem)
            af = *(const bf8_t*)(cea + (size_t)(p + m) * EDGE_DIM + quad * 8);
        else if (quad == 2)
            af[0] = (short)0x3F80;
        int sr[4];
        #pragma unroll
        for (int r = 0; r < 4; ++r) {
            int idx = p + quad * 4 + r; if (idx >= pe) idx = pe - 1;
            sr[r] = csr_src[idx];
        }
        bf4_t hrow[4];
        #pragma unroll
        for (int r = 0; r < 4; ++r)
            hrow[r] = *(const bf4_t*)(Hbp + (size_t)sr[r] * HID + m * 8 + half * 4);
        f32x4 d[4];
        #pragma unroll
        for (int t = 0; t < 4; ++t)
            d[t] = __builtin_amdgcn_mfma_f32_16x16x32_bf16(af, bw[t], zc, 0, 0, 0);
        #pragma unroll
        for (int t = 0; t < 4; ++t)
            #pragma unroll
            for (int r = 0; r < 4; ++r)
                if (quad * 4 + r < rem)
                    acc[t] += fmaxf(bf2f((unsigned short)hrow[r][t]) + d[t][r], 0.0f);
    }
    #pragma unroll
    for (int t = 0; t < 4; ++t) {
        acc[t] += __shfl_xor(acc[t], 16);
        acc[t] += __shfl_xor(acc[t], 32);
    }
    // lane (quad,m) writes feature (half*4+quad)*16 + m ; add self term from Hbp
    float asel = (quad == 0) ? acc[0] : (quad == 1) ? acc[1] : (quad == 2) ? acc[2] : acc[3];
    float self_ = bf2f(Hbp[(size_t)n * HID + m * 8 + half * 4 + quad]);
    Abp[(size_t)n * HID + (half * 4 + quad) * 16 + m] = f2bf(asel + self_);
}

// ==================== node MLP v2: feature-split wave pairs (A bf16 in, H bf16 out) ====================
// Wave pair (tile, role): role computes output features role*64..role*64+63 of BOTH
// layers for the pair's 16 nodes. Layer-1 halves meet in the shared LDS h1 tile.
#define MLP_NODES_PER_BLOCK 32
__global__ __launch_bounds__(256, 6) void k_mlp_mfma(
    const unsigned short* __restrict__ Abp, const int* __restrict__ batch,
    const unsigned short* __restrict__ wt1, const unsigned short* __restrict__ wt2,
    const float* __restrict__ b1, const float* __restrict__ b2,
    unsigned short* __restrict__ Hb, float* __restrict__ gsum, float* __restrict__ gsq) {
    __shared__ short h1s[2][16 * HS];
    int w = threadIdx.x >> 6;
    int lane = threadIdx.x & 63;
    int m = lane & 15;
    int quad = lane >> 4;
    int tile = w >> 1, role = w & 1;
    int nb = blockIdx.x * MLP_NODES_PER_BLOCK + tile * 16;
    short* hw = h1s[tile];
    int fbase = role * 64;

    int nclamp = nb + m; if (nclamp >= N_NODES) nclamp = N_NODES - 1;
    const unsigned short* Ap = Abp + (size_t)nclamp * HID;
    f32x4 acc1[4];
    #pragma unroll
    for (int t = 0; t < 4; ++t) {
        float bv = b1[fbase + t * 16 + m];
        acc1[t] = (f32x4){bv, bv, bv, bv};
    }
    #pragma unroll
    for (int s_ = 0; s_ < 4; ++s_) {
        int k0 = s_ * 32 + quad * 8;
        bf8_t af = *(const bf8_t*)(Ap + k0);
        #pragma unroll
        for (int t = 0; t < 4; ++t) {
            bf8_t bf = *(const bf8_t*)(wt1 + (size_t)(fbase + t * 16 + m) * HID + k0);
            acc1[t] = __builtin_amdgcn_mfma_f32_16x16x32_bf16(af, bf, acc1[t], 0, 0, 0);
        }
    }
    #pragma unroll
    for (int t = 0; t < 4; ++t)
        #pragma unroll
        for (int r = 0; r < 4; ++r) {
            float v = fmaxf(acc1[t][r], 0.0f);
            hw[(quad * 4 + r) * HS + fbase + t * 16 + m] = (short)f2bf(v);
        }
    __syncthreads();
    f32x4 acc2[4];
    #pragma unroll
    for (int t = 0; t < 4; ++t) {
        float bv = b2[fbase + t * 16 + m];
        acc2[t] = (f32x4){bv, bv, bv, bv};
    }
    #pragma unroll
    for (int s_ = 0; s_ < 4; ++s_) {
        int k0 = s_ * 32 + quad * 8;
        bf8_t af = *(const bf8_t*)(hw + m * HS + k0);
        #pragma unroll
        for (int t = 0; t < 4; ++t) {
            bf8_t bf = *(const bf8_t*)(wt2 + (size_t)(fbase + t * 16 + m) * HID + k0);
            acc2[t] = __builtin_amdgcn_mfma_f32_16x16x32_bf16(af, bf, acc2[t], 0, 0, 0);
        }
    }
    #pragma unroll
    for (int t = 0; t < 4; ++t)
        #pragma unroll
        for (int r = 0; r < 4; ++r) {
            int node = nb + quad * 4 + r;
            if (node < N_NODES) Hb[(size_t)node * HID + fbase + t * 16 + m] = f2bf(acc2[t][r]);
        }
    int blast = nb + 15 < N_NODES ? batch[nb + 15] : -1;
    int g0 = batch[nb < N_NODES ? nb : N_NODES - 1];
    if (nb + 15 < N_NODES && g0 == blast) {
        #pragma unroll
        for (int t = 0; t < 4; ++t) {
            float s = 0.0f, q = 0.0f;
            #pragma unroll
            for (int r = 0; r < 4; ++r) { float v = acc2[t][r]; s += v; q += v * v; }
            s += __shfl_xor(s, 16); q += __shfl_xor(q, 16);
            s += __shfl_xor(s, 32); q += __shfl_xor(q, 32);
            if (quad == 0) {
                atomicAdd(&gsum[g0 * HID + fbase + t * 16 + m], s);
                atomicAdd(&gsq[g0 * HID + fbase + t * 16 + m], q);
            }
        }
    } else {
        #pragma unroll
        for (int t = 0; t < 4; ++t)
            #pragma unroll
            for (int r = 0; r < 4; ++r) {
                int node = nb + quad * 4 + r;
                if (node < N_NODES) {
                    int g = batch[node];
                    float v = acc2[t][r];
                    atomicAdd(&gsum[g * HID + fbase + t * 16 + m], v);
                    atomicAdd(&gsq[g * HID + fbase + t * 16 + m], v * v);
                }
            }
    }
}

// ==================== normalize + relu -> Hbp (+ pool on last layer), stats inline ====================
#define NORM_N 8
__global__ __launch_bounds__(HID) void k_norm(
    const unsigned short* __restrict__ Hb, const int* __restrict__ batch,
    const float* __restrict__ gsum, const float* __restrict__ gsq,
    const float* __restrict__ cnt,
    const float* __restrict__ gw, const float* __restrict__ gb,
    const float* __restrict__ gms,
    unsigned short* __restrict__ Hbp, float* __restrict__ pool, int accumulate) {
    int n0 = blockIdx.x * NORM_N;
    int t = threadIdx.x;
    int m = t & 15, tt = t >> 4;
    float ms = gms[t], gwt = gw[t], gbt = gb[t];
    int g0 = batch[n0], gN = batch[n0 + NORM_N - 1];
    if (g0 == gN) {
        float c = fmaxf(cnt[g0], 1.0f);
        float mean = gsum[g0 * HID + t] / c;
        float msq  = gsq[g0 * HID + t] / c;
        float var = fmaxf(msq - mean * mean * ms * (2.0f - ms), 0.0f);
        float ssc = gwt * rsqrtf(var + EPS);
        float sof = gbt - ssc * mean * ms;
        float ps = 0.0f;
        #pragma unroll
        for (int i = 0; i < NORM_N; ++i) {
            float v = fmaxf(bf2f(Hb[(size_t)(n0 + i) * HID + t]) * ssc + sof, 0.0f);
            Hbp[(size_t)(n0 + i) * HID + m * 8 + tt] = f2bf(v);
            ps += v;
        }
        if (accumulate) atomicAdd(&pool[g0 * HID + t], ps);
    } else {
        #pragma unroll
        for (int i = 0; i < NORM_N; ++i) {
            int g = batch[n0 + i];
            float c = fmaxf(cnt[g], 1.0f);
            float mean = gsum[g * HID + t] / c;
            float msq  = gsq[g * HID + t] / c;
            float var = fmaxf(msq - mean * mean * ms * (2.0f - ms), 0.0f);
            float ssc = gwt * rsqrtf(var + EPS);
            float sof = gbt - ssc * mean * ms;
            float v = fmaxf(bf2f(Hb[(size_t)(n0 + i) * HID + t]) * ssc + sof, 0.0f);
            Hbp[(size_t)(n0 + i) * HID + m * 8 + tt] = f2bf(v);
            if (accumulate) atomicAdd(&pool[g * HID + t], v);
        }
    }
}

// ==================== output head ====================
__global__ __launch_bounds__(HID) void k_head(
    const float* __restrict__ pool,
    const float* __restrict__ fw1, const float* __restrict__ fb1,
    const float* __restrict__ fw2, const float* __restrict__ fb2,
    float* __restrict__ out) {
    __shared__ float ps[HID];
    __shared__ float red[2];
    int g = blockIdx.x;
    int t = threadIdx.x;
    ps[t] = pool[g * HID + t];
    __syncthreads();
    float acc = fb1[t];
    #pragma unroll 4
    for (int k = 0; k < HID; ++k) acc = fmaf(ps[k], fw1[k * HID + t], acc);
    float p = fmaxf(acc, 0.0f) * fw2[t];
    #pragma unroll
    for (int off = 32; off > 0; off >>= 1) p += __shfl_down(p, off, 64);
    if ((t & 63) == 0) red[t >> 6] = p;
    __syncthreads();
    if (t == 0) out[g] = red[0] + red[1] + fb2[0];
}

extern "C" void kernel_launch(void* const* d_in, const int* in_sizes, int n_in,
                              void* d_out, int out_size, void* d_ws, size_t ws_size,
                              hipStream_t stream) {
    const float* x     = (const float*)d_in[0];
    const int*   ei    = (const int*)d_in[1];
    const float* ea    = (const float*)d_in[2];
    const int*   batch = (const int*)d_in[3];
    const float* lw1 = (const float*)d_in[4];
    const float* lb1 = (const float*)d_in[5];
    const float* lw2 = (const float*)d_in[6];
    const float* lb2 = (const float*)d_in[7];
    const float* pw1 = (const float*)d_in[8];
    const float* pb1 = (const float*)d_in[9];
    const float* pw2 = (const float*)d_in[10];
    const float* pb2 = (const float*)d_in[11];
    const float* ew  = (const float*)d_in[12];
    const float* eb  = (const float*)d_in[13];
    const float* nw1 = (const float*)d_in[14];
    const float* nb1 = (const float*)d_in[15];
    const float* nw2 = (const float*)d_in[16];
    const float* nb2 = (const float*)d_in[17];
    const float* gw  = (const float*)d_in[18];
    const float* gb  = (const float*)d_in[19];
    const float* gms = (const float*)d_in[20];
    const float* fw1 = (const float*)d_in[21];
    const float* fb1 = (const float*)d_in[22];
    const float* fw2 = (const float*)d_in[23];
    const float* fb2 = (const float*)d_in[24];
    float* out = (float*)d_out;

    float* ws   = (float*)d_ws;
    float* H    = ws;                          // 12.8MB: bf16 Hb / csr_se staging (dead until layers)
    float* A    = H    + (size_t)N_NODES * HID;// 25.6MB: Abp bf16 (lower) + bkt (upper)
    float* gsum = A    + (size_t)N_NODES * HID;// 3 * NGRAPH*HID (per-layer)
    float* gsq  = gsum + NLAYERS * NGRAPH * HID;
    float* pool = gsq  + NLAYERS * NGRAPH * HID;
    float* cnt  = pool + NGRAPH * HID;         // 128 f
    int* bcnt_pad  = (int*)(cnt + NGRAPH);     // NB*16 = 6256 ints (padded counters)
    int* boff      = bcnt_pad + NB * 16;       // NB+1
    int* row_start = boff + 512;               // 50000
    int* row_end   = row_start + N_NODES;      // 50000
    int* csr_src   = row_end + N_NODES;        // 800000 (CSR-ordered src, 4B)
    unsigned short* cea  = (unsigned short*)(csr_src + N_EDGES);    // 12,800,000 bf16 (CSR order)
    unsigned short* wt   = cea + (size_t)N_EDGES * EDGE_DIM;        // 98304
    unsigned short* wenc = wt + NLAYERS * 2 * HID * HID;            // 49152
    unsigned short* wte  = wenc + 49152;                            // 12288
    unsigned short* Hbp  = wte + NLAYERS * 8 * 64 * 8;              // 6,400,000 bf16 (12.8 MB)
    unsigned short* Hb   = (unsigned short*)H;                      // 12.8 MB
    unsigned short* Abp  = (unsigned short*)A;                      // 12.8 MB
    int2* bkt    = (int2*)(Abp + (size_t)N_NODES * HID);            // NB*BCAP*8B = 12.7 MB (A upper)
    int2* csr_se = (int2*)H;                                        // 6.4 MB staging in H region

    const int* srcs = ei;
    const int* dsts = ei + N_EDGES;

    // ---- init + bucket CSR build + weight conversion ----
    k_init<<<(NLAYERS * NGRAPH * HID + 255) / 256, 256, 0, stream>>>(
        bcnt_pad, pool, gsum, gsq, batch, cnt);
    k_wall<<<(159744 + 255) / 256, 256, 0, stream>>>(
        nw1, nw2, lw1, pw1, lw2, pw2, ew, eb, wt, wenc, wte);
    k_bfill<<<(N_EDGES + 255) / 256, 256, 0, stream>>>(srcs, dsts, bcnt_pad, bkt);
    k_bscan<<<1, 512, 0, stream>>>(bcnt_pad, boff);
    k_bcsr<<<NB, 256, 0, stream>>>(bcnt_pad, boff, bkt, row_start, row_end, csr_se);
    k_reorder<<<(N_EDGES + 255) / 256, 256, 0, stream>>>(csr_se, ea, csr_src, cea);

    // ---- encoder (MFMA, role-split waves) -> Hbp ----
    k_encoder_mfma<<<(N_NODES + 31) / 32, 256, 0, stream>>>(
        x, wenc, lb1, lb2, pb1, pb2, Hbp);

    // ---- layers: gather, MLP, norm (stats inline) ----
    int mlp_blocks = (N_NODES + MLP_NODES_PER_BLOCK - 1) / MLP_NODES_PER_BLOCK;
    for (int l = 0; l < NLAYERS; ++l) {
        k_gather<<<N_NODES / 2, 256, 0, stream>>>(
            csr_src, cea, row_start, row_end,
            wte + (size_t)l * 4096, Hbp, Abp);
        k_mlp_mfma<<<mlp_blocks, 256, 0, stream>>>(
            Abp, batch,
            wt + (size_t)l * 2 * HID * HID,
            wt + (size_t)l * 2 * HID * HID + HID * HID,
            nb1 + l * HID, nb2 + l * HID,
            Hb, gsum + (size_t)l * NGRAPH * HID, gsq + (size_t)l * NGRAPH * HID);
        k_norm<<<N_NODES / NORM_N, HID, 0, stream>>>(
            Hb, batch,
            gsum + (size_t)l * NGRAPH * HID, gsq + (size_t)l * NGRAPH * HID,
            cnt, gw + l * HID, gb + l * HID, gms + l * HID,
            Hbp, pool, (l == NLAYERS - 1) ? 1 : 0);
    }
    k_head<<<NGRAPH, HID, 0, stream>>>(pool, fw1, fb1, fw2, fb2, out);
}